// Round 5
// baseline (617.653 us; speedup 1.0000x reference)
//
#include <hip/hip_runtime.h>

typedef __bf16 bf16;
typedef __bf16 bf16x8 __attribute__((ext_vector_type(8)));
typedef __bf16 bf16x4 __attribute__((ext_vector_type(4)));
typedef float  floatx4 __attribute__((ext_vector_type(4)));

#define B_ 4
#define T_ 2048
#define E_ 1024
#define H_ 16
#define D_ 64
#define NTE_ (B_ * T_ * E_)  // 8388608 elems

#define NEG_BIG (-1e30f)

// ---- static device memory ------------------------------------------------
// bf16 staging for all fp32 inputs:
#define OFF_CQ   0ull
#define OFF_CK   (OFF_CQ + (unsigned long long)NTE_)
#define OFF_CV   (OFF_CK + (unsigned long long)NTE_)
#define OFF_COS  (OFF_CV + (unsigned long long)NTE_)
#define OFF_SIN  (OFF_COS + 65536ull)
#define OFF_WQ   (OFF_SIN + 65536ull)
#define OFF_WK   (OFF_WQ + 1048576ull)
#define OFF_WV   (OFF_WK + 1048576ull)
#define OFF_WO   (OFF_WV + 1048576ull)
#define OFF_BQ   (OFF_WO + 1048576ull)
#define OFF_BK   (OFF_BQ + 1024ull)
#define OFF_BV   (OFF_BK + 1024ull)
#define OFF_BO   (OFF_BV + 1024ull)
#define CONV_TOT (OFF_BO + 1024ull)
__device__ bf16 g_conv[CONV_TOT];
// Pipeline scratch: qp | kp | vp | vt | op
__device__ bf16 g_scratch[5ull * NTE_];

__device__ __forceinline__ floatx4 mfma16(bf16x8 a, bf16x8 b, floatx4 c) {
  return __builtin_amdgcn_mfma_f32_16x16x32_bf16(a, b, c, 0, 0, 0);
}

// ---------------------------------------------------------------------------
// fp32 -> bf16 conversion (interface is fp32 per the reference; all-rounds
// evidence now consistent with that: fp32-as-bf16 reads gave NaN, bf16
// writes into the fp32 out buffer gave the 2.37 same-scale scramble).
// ---------------------------------------------------------------------------
__global__ __launch_bounds__(256) void convert_f32_bf16(const float4* __restrict__ src,
                                                        bf16x4* __restrict__ dst,
                                                        int n4) {
  int i0 = blockIdx.x * 256 + threadIdx.x;
  int stride = gridDim.x * 256;
  for (int i = i0; i < n4; i += stride) {
    float4 v = src[i];
    bf16x4 o;
    o[0] = (bf16)v.x; o[1] = (bf16)v.y; o[2] = (bf16)v.z; o[3] = (bf16)v.w;
    dst[i] = o;
  }
}

// ---------------------------------------------------------------------------
// GEMM: Y = X @ W^T + bias.  X: M x 1024 row-major bf16, W: (N,K) row-major
// bf16 (= B^T layout), Y templated (bf16 for internal stages, float for the
// final projection into d_out).  Tile 128x128, 4 waves (2x2 of 64x64), BK=32.
// A-frag: A[m=lane&15][k=(lane>>4)*8+j]; B-frag holds W[n=lane&15][k=...]
// C/D:    col(n)=lane&15, row(m)=(lane>>4)*4+reg   (m89/m91-verified)
// ---------------------------------------------------------------------------
template <typename OUT_T>
__global__ __launch_bounds__(256) void gemm_bt(const bf16* __restrict__ X,
                                               const bf16* __restrict__ W,
                                               const bf16* __restrict__ bias,
                                               OUT_T* __restrict__ Y) {
  constexpr int K = 1024, N = 1024;
  __shared__ bf16 sA[128 * 32];
  __shared__ bf16 sB[128 * 32];
  const int tid = threadIdx.x;
  const int w = tid >> 6;
  const int l = tid & 63;
  const int q = l >> 4;
  const int r = l & 15;
  const int M0 = blockIdx.x * 128;
  const int N0 = blockIdx.y * 128;
  const int wm = (w >> 1) * 64, wn = (w & 1) * 64;

  floatx4 acc[4][4];
  for (int mi = 0; mi < 4; ++mi)
    for (int ni = 0; ni < 4; ++ni) acc[mi][ni] = (floatx4){0.f, 0.f, 0.f, 0.f};

  for (int k0 = 0; k0 < K; k0 += 32) {
    __syncthreads();
#pragma unroll
    for (int i = 0; i < 2; ++i) {
      int idx = i * 256 + tid;
      int row = idx >> 2, cc = (idx & 3) << 3;  // [128 rows][32 cols]
      *(bf16x8*)(sA + row * 32 + cc) =
          *(const bf16x8*)(X + (size_t)(M0 + row) * K + k0 + cc);
      *(bf16x8*)(sB + row * 32 + cc) =
          *(const bf16x8*)(W + (size_t)(N0 + row) * K + k0 + cc);
    }
    __syncthreads();

    bf16x8 a[4], b[4];
#pragma unroll
    for (int mi = 0; mi < 4; ++mi)
      a[mi] = *(const bf16x8*)(sA + (wm + mi * 16 + r) * 32 + q * 8);
#pragma unroll
    for (int ni = 0; ni < 4; ++ni)
      b[ni] = *(const bf16x8*)(sB + (wn + ni * 16 + r) * 32 + q * 8);
#pragma unroll
    for (int mi = 0; mi < 4; ++mi)
#pragma unroll
      for (int ni = 0; ni < 4; ++ni) acc[mi][ni] = mfma16(a[mi], b[ni], acc[mi][ni]);
  }

#pragma unroll
  for (int mi = 0; mi < 4; ++mi) {
    int rowbase = M0 + wm + mi * 16 + q * 4;
#pragma unroll
    for (int ni = 0; ni < 4; ++ni) {
      int col = N0 + wn + ni * 16 + r;
      float bv = (float)bias[col];
#pragma unroll
      for (int rr = 0; rr < 4; ++rr) {
        Y[(size_t)(rowbase + rr) * N + col] = (OUT_T)(acc[mi][ni][rr] + bv);
      }
    }
  }
}

// ---------------------------------------------------------------------------
// RMSNorm + RoPE, in place on qp and kp. One 16-lane group per (b,t,h) row
// of 64 elems; lane j holds elems 4j..4j+3.
// ---------------------------------------------------------------------------
__global__ __launch_bounds__(256) void rmsnorm_rope() {
  bf16* qp = g_scratch;
  bf16* kp = g_scratch + (unsigned long long)NTE_;
  const bf16* cosb = g_conv + OFF_COS;
  const bf16* sinb = g_conv + OFF_SIN;
  constexpr int HR = B_ * T_ * H_;  // 131072 rows per array
  int gid = blockIdx.x * 16 + (threadIdx.x >> 4);
  int j = threadIdx.x & 15;
  bf16* base = (gid < HR) ? qp : kp;
  int row = gid & (HR - 1);
  int t = (row >> 4) & (T_ - 1);  // row = (b*T + t)*H + h
  bf16* p = base + (size_t)row * 64 + j * 4;

  bf16x4 xv = *(const bf16x4*)p;
  float x[4], ss = 0.f;
#pragma unroll
  for (int i = 0; i < 4; ++i) { x[i] = (float)xv[i]; ss += x[i] * x[i]; }
#pragma unroll
  for (int m = 1; m < 16; m <<= 1) ss += __shfl_xor(ss, m, 64);
  float rs = rsqrtf(ss * (1.0f / 64.0f) + 1e-6f);

  float y[4], pr[4];
#pragma unroll
  for (int i = 0; i < 4; ++i) y[i] = x[i] * rs;
#pragma unroll
  for (int i = 0; i < 4; ++i) pr[i] = __shfl_xor(y[i], 8, 64);

  int dbase = (j & 7) * 4;  // d' in [0,32)
  bf16x4 ov;
#pragma unroll
  for (int i = 0; i < 4; ++i) {
    float c = (float)cosb[t * 32 + dbase + i];
    float s = (float)sinb[t * 32 + dbase + i];
    float o = (j < 8) ? (y[i] * c - pr[i] * s) : (y[i] * c + pr[i] * s);
    ov[i] = (bf16)o;
  }
  *(bf16x4*)p = ov;
}

// ---------------------------------------------------------------------------
// Transpose V: vp (b,t,h,d) -> vt (b,h,d,t). One block per (b,h, 64-t chunk).
// ---------------------------------------------------------------------------
__global__ __launch_bounds__(256) void transpose_v() {
  const bf16* vp = g_scratch + 2ull * NTE_;
  bf16* vt = g_scratch + 3ull * NTE_;
  __shared__ bf16 tile[64][72];  // +8 pad
  int bid = blockIdx.x;
  int tt = bid & 31;       // T/64 = 32 chunks
  int bh = bid >> 5;       // b*H + h
  int h = bh & 15, b = bh >> 4;
  int t0 = tt * 64;
  int tid = threadIdx.x;
#pragma unroll
  for (int i = 0; i < 2; ++i) {
    int idx = i * 256 + tid;
    int row = idx >> 3, cc = (idx & 7) * 8;  // row = t_local, cc = d offset
    bf16x8 v = *(const bf16x8*)(vp + (size_t)(b * T_ + t0 + row) * E_ + h * D_ + cc);
#pragma unroll
    for (int jj = 0; jj < 8; ++jj) tile[row][cc + jj] = v[jj];
  }
  __syncthreads();
#pragma unroll
  for (int i = 0; i < 2; ++i) {
    int idx = i * 256 + tid;
    int d = idx >> 3, tc = (idx & 7) * 8;
    bf16x8 v;
#pragma unroll
    for (int jj = 0; jj < 8; ++jj) v[jj] = tile[tc + jj][d];
    *(bf16x8*)(vt + ((size_t)bh * D_ + d) * T_ + t0 + tc) = v;
  }
}

// ---------------------------------------------------------------------------
// Flash attention, causal. Block = 4 waves x 16 Q rows = 64 Q rows for one
// (b,h). Finite masking; online softmax per C-row; P: C-layout -> LDS ->
// A-layout (m120 pattern).
// ---------------------------------------------------------------------------
__global__ __launch_bounds__(256) void flash_attn() {
  const bf16* qp = g_scratch;
  const bf16* kp = g_scratch + (unsigned long long)NTE_;
  const bf16* vt = g_scratch + 3ull * NTE_;
  bf16* op = g_scratch + 4ull * NTE_;

  __shared__ bf16 sK[64 * 64];
  __shared__ bf16 sV[64 * 64];      // [d][key]
  __shared__ bf16 sP[4 * 16 * 64];  // wave-private 16x64 strips

  int bid = blockIdx.x;
  int qt = bid & 31;
  int bh = bid >> 5;
  int h = bh & 15, b = bh >> 4;
  int Q0 = qt * 64;
  int tid = threadIdx.x, w = tid >> 6, l = tid & 63, q = l >> 4, r = l & 15;

  int qrow = Q0 + w * 16 + r;
  const bf16* qbase = qp + (size_t)(b * T_ + qrow) * E_ + h * D_;
  bf16x8 qa[2];
  qa[0] = *(const bf16x8*)(qbase + q * 8);
  qa[1] = *(const bf16x8*)(qbase + 32 + q * 8);

  float m_i[4], l_i[4];
  floatx4 o_acc[4];
#pragma unroll
  for (int i = 0; i < 4; ++i) {
    m_i[i] = NEG_BIG;
    l_i[i] = 0.f;
    o_acc[i] = (floatx4){0.f, 0.f, 0.f, 0.f};
  }

  bf16* pw = sP + w * (16 * 64);

  for (int kt0 = 0; kt0 <= Q0; kt0 += 64) {
    __syncthreads();
#pragma unroll
    for (int i = 0; i < 2; ++i) {
      int idx = i * 256 + tid;
      int row = idx >> 3, cc = (idx & 7) * 8;
      *(bf16x8*)(sK + row * 64 + cc) =
          *(const bf16x8*)(kp + (size_t)(b * T_ + kt0 + row) * E_ + h * D_ + cc);
      *(bf16x8*)(sV + row * 64 + cc) =
          *(const bf16x8*)(vt + ((size_t)bh * D_ + row) * T_ + kt0 + cc);
    }
    __syncthreads();

    floatx4 s[4];
#pragma unroll
    for (int sc = 0; sc < 4; ++sc) {
      bf16x8 kb0 = *(const bf16x8*)(sK + (sc * 16 + r) * 64 + q * 8);
      bf16x8 kb1 = *(const bf16x8*)(sK + (sc * 16 + r) * 64 + 32 + q * 8);
      floatx4 a = (floatx4){0.f, 0.f, 0.f, 0.f};
      a = mfma16(qa[0], kb0, a);
      a = mfma16(qa[1], kb1, a);
      s[sc] = a;
    }

    float rowmax[4] = {NEG_BIG, NEG_BIG, NEG_BIG, NEG_BIG};
#pragma unroll
    for (int sc = 0; sc < 4; ++sc) {
      int kglob = kt0 + sc * 16 + r;
#pragma unroll
      for (int rr = 0; rr < 4; ++rr) {
        int qglob = Q0 + w * 16 + q * 4 + rr;
        float v = fminf(s[sc][rr] * 0.125f, 1e30f);
        v = (kglob <= qglob) ? v : NEG_BIG;
        s[sc][rr] = v;
        rowmax[rr] = fmaxf(rowmax[rr], v);
      }
    }
#pragma unroll
    for (int rr = 0; rr < 4; ++rr)
#pragma unroll
      for (int m = 1; m < 16; m <<= 1)
        rowmax[rr] = fmaxf(rowmax[rr], __shfl_xor(rowmax[rr], m, 64));

    float alpha[4];
#pragma unroll
    for (int rr = 0; rr < 4; ++rr) {
      float mnew = fmaxf(m_i[rr], rowmax[rr]);
      alpha[rr] = __expf(m_i[rr] - mnew);
      m_i[rr] = mnew;
    }

    float rowsum[4] = {0.f, 0.f, 0.f, 0.f};
#pragma unroll
    for (int sc = 0; sc < 4; ++sc)
#pragma unroll
      for (int rr = 0; rr < 4; ++rr) {
        float p = __expf(s[sc][rr] - m_i[rr]);
        s[sc][rr] = p;
        rowsum[rr] += p;
      }
#pragma unroll
    for (int rr = 0; rr < 4; ++rr)
#pragma unroll
      for (int m = 1; m < 16; m <<= 1) rowsum[rr] += __shfl_xor(rowsum[rr], m, 64);
#pragma unroll
    for (int rr = 0; rr < 4; ++rr) l_i[rr] = l_i[rr] * alpha[rr] + rowsum[rr];

#pragma unroll
    for (int sc = 0; sc < 4; ++sc)
#pragma unroll
      for (int rr = 0; rr < 4; ++rr)
        pw[(q * 4 + rr) * 64 + sc * 16 + r] = (bf16)s[sc][rr];
    asm volatile("s_waitcnt lgkmcnt(0)" ::: "memory");

#pragma unroll
    for (int dt = 0; dt < 4; ++dt)
#pragma unroll
      for (int rr = 0; rr < 4; ++rr) o_acc[dt][rr] *= alpha[rr];

#pragma unroll
    for (int kk = 0; kk < 2; ++kk) {
      bf16x8 pa = *(const bf16x8*)(pw + r * 64 + kk * 32 + q * 8);
#pragma unroll
      for (int dt = 0; dt < 4; ++dt) {
        bf16x8 vb = *(const bf16x8*)(sV + (dt * 16 + r) * 64 + kk * 32 + q * 8);
        o_acc[dt] = mfma16(pa, vb, o_acc[dt]);
      }
    }
  }

#pragma unroll
  for (int dt = 0; dt < 4; ++dt)
#pragma unroll
    for (int rr = 0; rr < 4; ++rr) {
      int t = Q0 + w * 16 + q * 4 + rr;
      float oo = o_acc[dt][rr] / l_i[rr];  // l_i >= 1 (diagonal term)
      op[(size_t)(b * T_ + t) * E_ + h * D_ + dt * 16 + r] = (bf16)oo;
    }
}

// ---------------------------------------------------------------------------
extern "C" void kernel_launch(void* const* d_in, const int* in_sizes, int n_in,
                              void* d_out, int out_size, void* d_ws, size_t ws_size,
                              hipStream_t stream) {
  float* out = (float*)d_out;  // fp32 output, per reference

  void* cvp_ = nullptr;
  void* sp_ = nullptr;
  hipGetSymbolAddress(&cvp_, HIP_SYMBOL(g_conv));
  hipGetSymbolAddress(&sp_, HIP_SYMBOL(g_scratch));
  bf16* cv_base = (bf16*)cvp_;
  bf16* sc_base = (bf16*)sp_;

  // convert all fp32 inputs (all except 3=mask) to bf16 staging
  const int src_idx[13] = {0, 1, 2, 4, 5, 6, 7, 8, 9, 10, 11, 12, 13};
  const unsigned long long dst_off[13] = {OFF_CQ, OFF_CK, OFF_CV, OFF_COS, OFF_SIN,
                                          OFF_WQ, OFF_BQ, OFF_WK, OFF_BK,
                                          OFF_WV, OFF_BV, OFF_WO, OFF_BO};
  for (int i = 0; i < 13; ++i) {
    int n4 = in_sizes[src_idx[i]] >> 2;
    int grid = (n4 + 255) / 256;
    if (grid > 2048) grid = 2048;
    if (grid < 1) grid = 1;
    convert_f32_bf16<<<dim3(grid), dim3(256), 0, stream>>>(
        (const float4*)d_in[src_idx[i]], (bf16x4*)(cv_base + dst_off[i]), n4);
  }

  bf16* qp = sc_base;                    // gemm outputs
  bf16* kp = sc_base + 1ull * NTE_;
  bf16* vp = sc_base + 2ull * NTE_;
  bf16* op = sc_base + 4ull * NTE_;

  dim3 gg(64, 8), bb(256);
  gemm_bt<bf16><<<gg, bb, 0, stream>>>(cv_base + OFF_CQ, cv_base + OFF_WQ, cv_base + OFF_BQ, qp);
  gemm_bt<bf16><<<gg, bb, 0, stream>>>(cv_base + OFF_CK, cv_base + OFF_WK, cv_base + OFF_BK, kp);
  gemm_bt<bf16><<<gg, bb, 0, stream>>>(cv_base + OFF_CV, cv_base + OFF_WV, cv_base + OFF_BV, vp);
  rmsnorm_rope<<<dim3(16384), bb, 0, stream>>>();
  transpose_v<<<dim3(2048), bb, 0, stream>>>();
  flash_attn<<<dim3(2048), bb, 0, stream>>>();
  gemm_bt<float><<<gg, bb, 0, stream>>>(op, cv_base + OFF_WO, cv_base + OFF_BO, out);
}